// Round 1
// baseline (648.105 us; speedup 1.0000x reference)
//
#include <hip/hip_runtime.h>

typedef unsigned short u16;
typedef short short8 __attribute__((ext_vector_type(8)));
typedef float f32x4 __attribute__((ext_vector_type(4)));

// ---------------- helpers ----------------
__device__ __forceinline__ u16 f2b(float f) {
  unsigned u = __float_as_uint(f);
  u = u + 0x7FFFu + ((u >> 16) & 1u);   // round-to-nearest-even
  return (u16)(u >> 16);
}
__device__ __forceinline__ float b2f(u16 b) {
  return __uint_as_float(((unsigned)b) << 16);
}

#define ASYNC_LD16(g, l)                                                                   \
  __builtin_amdgcn_global_load_lds((const __attribute__((address_space(1))) void*)(g),     \
                                   (__attribute__((address_space(3))) void*)(l), 16, 0, 0)

// ---------------- K0a: x fp32 -> bf16 ----------------
__global__ void convert_x(const float* __restrict__ x, u16* __restrict__ xb) {
  size_t i = ((size_t)blockIdx.x * 256 + threadIdx.x) * 4;  // 32768 blocks * 256 * 4 = 33554432
  float4 f = *(const float4*)(x + i);
  ushort4 o;
  o.x = f2b(f.x); o.y = f2b(f.y); o.z = f2b(f.z); o.w = f2b(f.w);
  *(ushort4*)(xb + i) = o;
}

// ---------------- K0b: weights fp32 -> bf16 (natural [o][e] layout) ----------------
__global__ void convert_w(const float* __restrict__ Wq, const float* __restrict__ Wk,
                          const float* __restrict__ Wv, const float* __restrict__ Wo,
                          u16* __restrict__ Wqkv, u16* __restrict__ Wob) {
  int idx = (blockIdx.x * 256 + threadIdx.x) * 4;  // 1024 blocks -> 2048*512 elems
  int row = idx >> 9;
  int col = idx & 511;
  const float* src = (row < 512)    ? Wq + (size_t)row * 512
                     : (row < 1024) ? Wk + (size_t)(row - 512) * 512
                     : (row < 1536) ? Wv + (size_t)(row - 1024) * 512
                                    : Wo + (size_t)(row - 1536) * 512;
  u16* dst = (row < 1536) ? Wqkv + (size_t)row * 512 : Wob + (size_t)(row - 1536) * 512;
  float4 f = *(const float4*)(src + col);
  ushort4 o;
  o.x = f2b(f.x); o.y = f2b(f.y); o.z = f2b(f.z); o.w = f2b(f.w);
  *(ushort4*)(dst + col) = o;
}

// ---------------- K1: fused QKV projection, C = x @ Wqkv^T, bias + elu+1 ----------------
// M=65536, N=1536, K=512.  128x128 tile / block, 4 waves, 16x16x32 bf16 MFMA.
__global__ void gemm_qkv(const u16* __restrict__ xb, const u16* __restrict__ Wqkv,
                         const float* __restrict__ bq, const float* __restrict__ bk,
                         const float* __restrict__ bv, u16* __restrict__ Qb,
                         u16* __restrict__ Kb, u16* __restrict__ Vb) {
  __shared__ u16 As[128 * 32];
  __shared__ u16 Bs[128 * 32];
  const int tid = threadIdx.x;
  const int blockM = blockIdx.y * 128;
  const int blockN = blockIdx.x * 128;
  const int lane = tid & 63;
  const int w = tid >> 6;
  const int wm = (w & 1) * 64;
  const int wn = (w >> 1) * 64;
  const int lr = lane & 15;
  const int qd = lane >> 4;

  f32x4 acc[4][4];
#pragma unroll
  for (int i = 0; i < 4; ++i)
#pragma unroll
    for (int j = 0; j < 4; ++j) acc[i][j] = {0.f, 0.f, 0.f, 0.f};

  for (int k0 = 0; k0 < 512; k0 += 32) {
    __syncthreads();
#pragma unroll
    for (int j = 0; j < 2; ++j) {
      int idx = j * 256 + tid;
      int row = idx >> 2, seg = idx & 3;
      ASYNC_LD16(xb + (size_t)(blockM + row) * 512 + k0 + seg * 8, As + idx * 8);
      ASYNC_LD16(Wqkv + (size_t)(blockN + row) * 512 + k0 + seg * 8, Bs + idx * 8);
    }
    __syncthreads();
    short8 a[4], b[4];
#pragma unroll
    for (int i = 0; i < 4; ++i) a[i] = *(const short8*)&As[(wm + i * 16 + lr) * 32 + qd * 8];
#pragma unroll
    for (int j = 0; j < 4; ++j) b[j] = *(const short8*)&Bs[(wn + j * 16 + lr) * 32 + qd * 8];
#pragma unroll
    for (int i = 0; i < 4; ++i)
#pragma unroll
      for (int j = 0; j < 4; ++j)
        acc[i][j] = __builtin_amdgcn_mfma_f32_16x16x32_bf16(a[i], b[j], acc[i][j], 0, 0, 0);
  }

  const int which = blockN >> 9;  // 0=q 1=k 2=v (128 | 512, so a block never straddles)
  u16* dst = which == 0 ? Qb : (which == 1 ? Kb : Vb);
  const float* bias = which == 0 ? bq : (which == 1 ? bk : bv);
  const int cb = blockN & 511;
#pragma unroll
  for (int j = 0; j < 4; ++j) {
    int col = cb + wn + j * 16 + lr;
    float bsv = bias[col];
#pragma unroll
    for (int i = 0; i < 4; ++i) {
#pragma unroll
      for (int r = 0; r < 4; ++r) {
        int row = blockM + wm + i * 16 + qd * 4 + r;
        float v = acc[i][j][r] + bsv;
        if (which < 2) v = (v > 0.f) ? v + 1.f : __expf(v);  // elu(v)+1
        dst[(size_t)row * 512 + col] = f2b(v);
      }
    }
  }
}

// ---------------- K2: per (b,r,h): ktv, ksum, z, out_h ----------------
__global__ void attn(const u16* __restrict__ Qb, const u16* __restrict__ Kb,
                     const u16* __restrict__ Vb, u16* __restrict__ Hb) {
  __shared__ u16 Ks[32 * 64];
  __shared__ u16 Vs[32 * 64];
  __shared__ u16 Qs[32 * 64];
  __shared__ float ktv[64 * 64];
  __shared__ float ksum[64];
  __shared__ float zs[32];

  const int tid = threadIdx.x;
  const int br = blockIdx.x >> 3;
  const int h = blockIdx.x & 7;
  const size_t tok0 = (size_t)br * 512;
  const int chan = h * 64;

  const int d0 = (tid >> 4) * 4;   // 0..60
  const int e0 = (tid & 15) * 4;   // 0..60

  float acc[4][4] = {};
  float ks4[4] = {};

  const int srow = tid >> 3, sseg = tid & 7;

  // phase A: ktv = K^T V, ksum = colsum(K)
  for (int ct = 0; ct < 16; ++ct) {
    size_t gbase = (tok0 + ct * 32 + srow) * 512 + chan + sseg * 8;
    *(uint4*)&Ks[tid * 8] = *(const uint4*)(Kb + gbase);
    *(uint4*)&Vs[tid * 8] = *(const uint4*)(Vb + gbase);
    __syncthreads();
#pragma unroll 4
    for (int cc = 0; cc < 32; ++cc) {
      ushort4 ku = *(const ushort4*)&Ks[cc * 64 + d0];
      ushort4 vu = *(const ushort4*)&Vs[cc * 64 + e0];
      float kf[4] = {b2f(ku.x), b2f(ku.y), b2f(ku.z), b2f(ku.w)};
      float vf[4] = {b2f(vu.x), b2f(vu.y), b2f(vu.z), b2f(vu.w)};
#pragma unroll
      for (int i = 0; i < 4; ++i)
#pragma unroll
        for (int j = 0; j < 4; ++j) acc[i][j] += kf[i] * vf[j];
      if ((tid & 15) == 0) {
#pragma unroll
        for (int i = 0; i < 4; ++i) ks4[i] += kf[i];
      }
    }
    __syncthreads();
  }
#pragma unroll
  for (int i = 0; i < 4; ++i)
#pragma unroll
    for (int j = 0; j < 4; ++j) ktv[(d0 + i) * 64 + e0 + j] = acc[i][j];
  if ((tid & 15) == 0) {
#pragma unroll
    for (int i = 0; i < 4; ++i) ksum[d0 + i] = ks4[i];
  }
  __syncthreads();

  // phase B: out_h = (Q @ ktv) * z
  const int cl = (tid >> 4) * 2;   // 0..30 (2 rows each)
  const int eb = (tid & 15) * 4;   // 0..60
  for (int ct = 0; ct < 16; ++ct) {
    *(uint4*)&Qs[tid * 8] = *(const uint4*)(Qb + (tok0 + ct * 32 + srow) * 512 + chan + sseg * 8);
    __syncthreads();
    if (tid < 32) {
      float s = 0.f;
#pragma unroll 8
      for (int d = 0; d < 64; ++d) s += b2f(Qs[tid * 64 + d]) * ksum[d];
      zs[tid] = 1.f / (s + 1e-6f);
    }
    __syncthreads();
    float o0[4] = {}, o1[4] = {};
#pragma unroll 8
    for (int d = 0; d < 64; ++d) {
      float q0 = b2f(Qs[cl * 64 + d]);
      float q1 = b2f(Qs[(cl + 1) * 64 + d]);
      f32x4 t = *(const f32x4*)&ktv[d * 64 + eb];
#pragma unroll
      for (int j = 0; j < 4; ++j) {
        o0[j] += q0 * t[j];
        o1[j] += q1 * t[j];
      }
    }
    float z0 = zs[cl], z1 = zs[cl + 1];
    ushort4 p0, p1;
    p0.x = f2b(o0[0] * z0); p0.y = f2b(o0[1] * z0); p0.z = f2b(o0[2] * z0); p0.w = f2b(o0[3] * z0);
    p1.x = f2b(o1[0] * z1); p1.y = f2b(o1[1] * z1); p1.z = f2b(o1[2] * z1); p1.w = f2b(o1[3] * z1);
    *(ushort4*)(Hb + (tok0 + ct * 32 + cl) * 512 + chan + eb) = p0;
    *(ushort4*)(Hb + (tok0 + ct * 32 + cl + 1) * 512 + chan + eb) = p1;
    __syncthreads();
  }
}

// ---------------- K3: out = out_h @ Wo^T + bo (fp32 out) ----------------
__global__ void gemm_out(const u16* __restrict__ Hb, const u16* __restrict__ Wob,
                         const float* __restrict__ bo, float* __restrict__ out) {
  __shared__ u16 As[128 * 32];
  __shared__ u16 Bs[128 * 32];
  const int tid = threadIdx.x;
  const int blockM = blockIdx.y * 128;
  const int blockN = blockIdx.x * 128;
  const int lane = tid & 63;
  const int w = tid >> 6;
  const int wm = (w & 1) * 64;
  const int wn = (w >> 1) * 64;
  const int lr = lane & 15;
  const int qd = lane >> 4;

  f32x4 acc[4][4];
#pragma unroll
  for (int i = 0; i < 4; ++i)
#pragma unroll
    for (int j = 0; j < 4; ++j) acc[i][j] = {0.f, 0.f, 0.f, 0.f};

  for (int k0 = 0; k0 < 512; k0 += 32) {
    __syncthreads();
#pragma unroll
    for (int j = 0; j < 2; ++j) {
      int idx = j * 256 + tid;
      int row = idx >> 2, seg = idx & 3;
      ASYNC_LD16(Hb + (size_t)(blockM + row) * 512 + k0 + seg * 8, As + idx * 8);
      ASYNC_LD16(Wob + (size_t)(blockN + row) * 512 + k0 + seg * 8, Bs + idx * 8);
    }
    __syncthreads();
    short8 a[4], b[4];
#pragma unroll
    for (int i = 0; i < 4; ++i) a[i] = *(const short8*)&As[(wm + i * 16 + lr) * 32 + qd * 8];
#pragma unroll
    for (int j = 0; j < 4; ++j) b[j] = *(const short8*)&Bs[(wn + j * 16 + lr) * 32 + qd * 8];
#pragma unroll
    for (int i = 0; i < 4; ++i)
#pragma unroll
      for (int j = 0; j < 4; ++j)
        acc[i][j] = __builtin_amdgcn_mfma_f32_16x16x32_bf16(a[i], b[j], acc[i][j], 0, 0, 0);
  }

#pragma unroll
  for (int j = 0; j < 4; ++j) {
    int col = blockN + wn + j * 16 + lr;
    float bsv = bo[col];
#pragma unroll
    for (int i = 0; i < 4; ++i) {
#pragma unroll
      for (int r = 0; r < 4; ++r) {
        int row = blockM + wm + i * 16 + qd * 4 + r;
        out[(size_t)row * 512 + col] = acc[i][j][r] + bsv;
      }
    }
  }
}

// ---------------- launch ----------------
extern "C" void kernel_launch(void* const* d_in, const int* in_sizes, int n_in,
                              void* d_out, int out_size, void* d_ws, size_t ws_size,
                              hipStream_t stream) {
  const float* x  = (const float*)d_in[0];
  const float* Wq = (const float*)d_in[1];
  const float* bq = (const float*)d_in[2];
  const float* Wk = (const float*)d_in[3];
  const float* bk = (const float*)d_in[4];
  const float* Wv = (const float*)d_in[5];
  const float* bv = (const float*)d_in[6];
  const float* Wo = (const float*)d_in[7];
  const float* bo = (const float*)d_in[8];
  float* out = (float*)d_out;

  char* ws = (char*)d_ws;
  u16* xb   = (u16*)(ws);                 // 64 MB  (reused as Hb after gemm_qkv consumes it)
  u16* Wqkv = (u16*)(ws + 0x04000000ull); // 1.5 MB
  u16* Wob  = (u16*)(ws + 0x04200000ull); // 0.5 MB
  u16* Qb   = (u16*)(ws + 0x04400000ull); // 64 MB
  u16* Kb   = (u16*)(ws + 0x08400000ull); // 64 MB
  u16* Vb   = (u16*)(ws + 0x0C400000ull); // 64 MB
  u16* Hb   = xb;

  hipLaunchKernelGGL(convert_x, dim3(32768), dim3(256), 0, stream, x, xb);
  hipLaunchKernelGGL(convert_w, dim3(1024), dim3(256), 0, stream, Wq, Wk, Wv, Wo, Wqkv, Wob);
  hipLaunchKernelGGL(gemm_qkv, dim3(12, 512), dim3(256), 0, stream, xb, Wqkv, bq, bk, bv, Qb, Kb, Vb);
  hipLaunchKernelGGL(attn, dim3(1024), dim3(256), 0, stream, Qb, Kb, Vb, Hb);
  hipLaunchKernelGGL(gemm_out, dim3(4, 512), dim3(256), 0, stream, Hb, Wob, bo, out);
}

// Round 2
// 504.471 us; speedup vs baseline: 1.2847x; 1.2847x over previous
//
#include <hip/hip_runtime.h>

typedef unsigned short u16;
typedef short short8 __attribute__((ext_vector_type(8)));
typedef float f32x4 __attribute__((ext_vector_type(4)));

// ---------------- helpers ----------------
__device__ __forceinline__ u16 f2b(float f) {
  unsigned u = __float_as_uint(f);
  u = u + 0x7FFFu + ((u >> 16) & 1u);   // round-to-nearest-even
  return (u16)(u >> 16);
}
__device__ __forceinline__ float b2f(u16 b) {
  return __uint_as_float(((unsigned)b) << 16);
}

#define ASYNC_LD16(g, l)                                                                   \
  __builtin_amdgcn_global_load_lds((const __attribute__((address_space(1))) void*)(g),     \
                                   (__attribute__((address_space(3))) void*)(l), 16, 0, 0)

// ---------------- K0a: x fp32 -> bf16 ----------------
__global__ void convert_x(const float* __restrict__ x, u16* __restrict__ xb) {
  size_t i = ((size_t)blockIdx.x * 256 + threadIdx.x) * 4;
  float4 f = *(const float4*)(x + i);
  ushort4 o;
  o.x = f2b(f.x); o.y = f2b(f.y); o.z = f2b(f.z); o.w = f2b(f.w);
  *(ushort4*)(xb + i) = o;
}

// ---------------- K0b: weights fp32 -> bf16 (natural [o][e] layout) ----------------
__global__ void convert_w(const float* __restrict__ Wq, const float* __restrict__ Wk,
                          const float* __restrict__ Wv, const float* __restrict__ Wo,
                          u16* __restrict__ Wqkv, u16* __restrict__ Wob) {
  int idx = (blockIdx.x * 256 + threadIdx.x) * 4;
  int row = idx >> 9;
  int col = idx & 511;
  const float* src = (row < 512)    ? Wq + (size_t)row * 512
                     : (row < 1024) ? Wk + (size_t)(row - 512) * 512
                     : (row < 1536) ? Wv + (size_t)(row - 1024) * 512
                                    : Wo + (size_t)(row - 1536) * 512;
  u16* dst = (row < 1536) ? Wqkv + (size_t)row * 512 : Wob + (size_t)(row - 1536) * 512;
  float4 f = *(const float4*)(src + col);
  ushort4 o;
  o.x = f2b(f.x); o.y = f2b(f.y); o.z = f2b(f.z); o.w = f2b(f.w);
  *(ushort4*)(dst + col) = o;
}

// ---------------- K1: fused QKV projection ----------------
// Q written token-major [tok][512]; K,V written TRANSPOSED per (b,r): [br][chan][tok]
__global__ void gemm_qkv(const u16* __restrict__ xb, const u16* __restrict__ Wqkv,
                         const float* __restrict__ bq, const float* __restrict__ bk,
                         const float* __restrict__ bv, u16* __restrict__ Qb,
                         u16* __restrict__ Ktg, u16* __restrict__ Vtg) {
  __shared__ u16 As[128 * 32];
  __shared__ u16 Bs[128 * 32];
  const int tid = threadIdx.x;
  const int blockM = blockIdx.y * 128;
  const int blockN = blockIdx.x * 128;
  const int lane = tid & 63;
  const int w = tid >> 6;
  const int wm = (w & 1) * 64;
  const int wn = (w >> 1) * 64;
  const int lr = lane & 15;
  const int qd = lane >> 4;

  f32x4 acc[4][4];
#pragma unroll
  for (int i = 0; i < 4; ++i)
#pragma unroll
    for (int j = 0; j < 4; ++j) acc[i][j] = {0.f, 0.f, 0.f, 0.f};

  for (int k0 = 0; k0 < 512; k0 += 32) {
    __syncthreads();
#pragma unroll
    for (int j = 0; j < 2; ++j) {
      int idx = j * 256 + tid;
      int row = idx >> 2, seg = idx & 3;
      ASYNC_LD16(xb + (size_t)(blockM + row) * 512 + k0 + seg * 8, As + idx * 8);
      ASYNC_LD16(Wqkv + (size_t)(blockN + row) * 512 + k0 + seg * 8, Bs + idx * 8);
    }
    __syncthreads();
    short8 a[4], b[4];
#pragma unroll
    for (int i = 0; i < 4; ++i) a[i] = *(const short8*)&As[(wm + i * 16 + lr) * 32 + qd * 8];
#pragma unroll
    for (int j = 0; j < 4; ++j) b[j] = *(const short8*)&Bs[(wn + j * 16 + lr) * 32 + qd * 8];
#pragma unroll
    for (int i = 0; i < 4; ++i)
#pragma unroll
      for (int j = 0; j < 4; ++j)
        acc[i][j] = __builtin_amdgcn_mfma_f32_16x16x32_bf16(a[i], b[j], acc[i][j], 0, 0, 0);
  }

  const int which = blockN >> 9;  // 0=q 1=k 2=v
  const float* bias = which == 0 ? bq : (which == 1 ? bk : bv);
  const int cb = blockN & 511;

  if (which == 0) {
    // Q: token-major, elu+1
#pragma unroll
    for (int j = 0; j < 4; ++j) {
      int col = cb + wn + j * 16 + lr;
      float bsv = bias[col];
#pragma unroll
      for (int i = 0; i < 4; ++i) {
#pragma unroll
        for (int r = 0; r < 4; ++r) {
          int row = blockM + wm + i * 16 + qd * 4 + r;
          float v = acc[i][j][r] + bsv;
          v = (v > 0.f) ? v + 1.f : __expf(v);
          Qb[(size_t)row * 512 + col] = f2b(v);
        }
      }
    }
  } else {
    // K/V: transposed store [br][chan][tok], elu+1 for K only
    u16* dstT = (which == 1) ? Ktg : Vtg;
    const int br = blockM >> 9;
    const int cb0 = (blockM & 511) + wm;
#pragma unroll
    for (int j = 0; j < 4; ++j) {
      int col = cb + wn + j * 16 + lr;
      float bsv = bias[col];
      size_t rowbase = (size_t)br * 262144 + (size_t)col * 512;
#pragma unroll
      for (int i = 0; i < 4; ++i) {
        int c0 = cb0 + i * 16 + qd * 4;
        ushort4 p;
        float v0 = acc[i][j][0] + bsv, v1 = acc[i][j][1] + bsv;
        float v2 = acc[i][j][2] + bsv, v3 = acc[i][j][3] + bsv;
        if (which == 1) {
          v0 = (v0 > 0.f) ? v0 + 1.f : __expf(v0);
          v1 = (v1 > 0.f) ? v1 + 1.f : __expf(v1);
          v2 = (v2 > 0.f) ? v2 + 1.f : __expf(v2);
          v3 = (v3 > 0.f) ? v3 + 1.f : __expf(v3);
        }
        p.x = f2b(v0); p.y = f2b(v1); p.z = f2b(v2); p.w = f2b(v3);
        *(ushort4*)&dstT[rowbase + c0] = p;
      }
    }
  }
}

// ---------------- K2: per (b,r,h): ktv, ksum, z, out_h — MFMA version ----------------
// Ktg/Vtg are [br][512 chan][512 tok]; Qb token-major; Hb token-major.
__global__ void attn(const u16* __restrict__ Qb, const u16* __restrict__ Ktg,
                     const u16* __restrict__ Vtg, u16* __restrict__ Hb) {
  __shared__ u16 KtS[64 * 32];     // [d][32 c]
  __shared__ u16 VtS[64 * 32];     // [e][32 c]
  __shared__ u16 QS[2 * 128 * 32]; // [kc][tok][32 d]
  __shared__ u16 ktvT[2 * 64 * 32];// [kc][e][32 d]  (bf16)
  __shared__ float part[256];
  __shared__ float ksumf[64];
  __shared__ float zs[128];

  const int tid = threadIdx.x;
  const int br = blockIdx.x >> 3;
  const int h = blockIdx.x & 7;
  const int h64 = h * 64;
  const size_t tok0 = (size_t)br * 512;
  const size_t tbase = (size_t)br * 262144 + (size_t)h64 * 512;

  const int lane = tid & 63;
  const int w = tid >> 6;
  const int lr = lane & 15;
  const int qd = lane >> 4;

  const int sc_chan = tid >> 2, sc_seg = tid & 3;  // staging: 64 chans x 4 segs of 8

  // ---------- phase A: ktv = K^T V (wave w owns d-strip [w*16, w*16+16)) ----------
  f32x4 acc[4];
#pragma unroll
  for (int j = 0; j < 4; ++j) acc[j] = {0.f, 0.f, 0.f, 0.f};
  float ks = 0.f;

  for (int ct = 0; ct < 16; ++ct) {
    __syncthreads();
    {
      size_t g = tbase + (size_t)sc_chan * 512 + ct * 32 + sc_seg * 8;
      ASYNC_LD16(Ktg + g, KtS + tid * 8);
      ASYNC_LD16(Vtg + g, VtS + tid * 8);
    }
    __syncthreads();
    short8 a = *(const short8*)&KtS[(w * 16 + lr) * 32 + qd * 8];
#pragma unroll
    for (int j = 0; j < 4; ++j) {
      short8 b = *(const short8*)&VtS[(j * 16 + lr) * 32 + qd * 8];
      acc[j] = __builtin_amdgcn_mfma_f32_16x16x32_bf16(a, b, acc[j], 0, 0, 0);
    }
    // ksum partial: thread owns (d = tid>>2, quarter cq = tid&3)
    ushort4 k0 = *(const ushort4*)&KtS[sc_chan * 32 + sc_seg * 8];
    ushort4 k1 = *(const ushort4*)&KtS[sc_chan * 32 + sc_seg * 8 + 4];
    ks += b2f(k0.x) + b2f(k0.y) + b2f(k0.z) + b2f(k0.w)
        + b2f(k1.x) + b2f(k1.y) + b2f(k1.z) + b2f(k1.w);
  }
  part[tid] = ks;
  // write ktvT [kc = w>>1][e][d' = (w&1)*16 + qd*4 + r] as bf16
  {
    int kc = w >> 1;
    int dp = (w & 1) * 16 + qd * 4;
#pragma unroll
    for (int j = 0; j < 4; ++j) {
      int e = j * 16 + lr;
      ushort4 p;
      p.x = f2b(acc[j][0]); p.y = f2b(acc[j][1]);
      p.z = f2b(acc[j][2]); p.w = f2b(acc[j][3]);
      *(ushort4*)&ktvT[kc * 2048 + e * 32 + dp] = p;
    }
  }
  __syncthreads();
  if (tid < 64)
    ksumf[tid] = part[tid * 4] + part[tid * 4 + 1] + part[tid * 4 + 2] + part[tid * 4 + 3];
  __syncthreads();

  // hoist B-fragments (ktv) — loop-invariant
  short8 bfr[4][2];
#pragma unroll
  for (int j = 0; j < 4; ++j)
#pragma unroll
    for (int kc = 0; kc < 2; ++kc)
      bfr[j][kc] = *(const short8*)&ktvT[kc * 2048 + (j * 16 + lr) * 32 + qd * 8];

  // ---------- phase B: out = (Q @ ktv) * z, 4 chunks of 128 tokens ----------
  for (int ct = 0; ct < 4; ++ct) {
    __syncthreads();
#pragma unroll
    for (int kc = 0; kc < 2; ++kc)
#pragma unroll
      for (int half = 0; half < 2; ++half)
        ASYNC_LD16(Qb + (tok0 + ct * 128 + half * 64 + sc_chan) * 512 + h64 + kc * 32 + sc_seg * 8,
                   QS + kc * 4096 + half * 2048 + tid * 8);
    __syncthreads();
    // z per token (skewed LDS walk, conflict-free)
    if (tid < 128) {
      float s = 0.f;
#pragma unroll 8
      for (int i = 0; i < 32; ++i) {
        int ix = (i + tid) & 31;
        s += b2f(QS[tid * 32 + ix]) * ksumf[ix];
        s += b2f(QS[4096 + tid * 32 + ix]) * ksumf[32 + ix];
      }
      zs[tid] = 1.f / (s + 1e-6f);
    }
    __syncthreads();
    // MFMA: wave w owns token strips (w*2+s)*16
#pragma unroll
    for (int s = 0; s < 2; ++s) {
      int mrow = (w * 2 + s) * 16 + lr;
      short8 a0 = *(const short8*)&QS[mrow * 32 + qd * 8];
      short8 a1 = *(const short8*)&QS[4096 + mrow * 32 + qd * 8];
      f32x4 o[4];
#pragma unroll
      for (int j = 0; j < 4; ++j) {
        o[j] = {0.f, 0.f, 0.f, 0.f};
        o[j] = __builtin_amdgcn_mfma_f32_16x16x32_bf16(a0, bfr[j][0], o[j], 0, 0, 0);
        o[j] = __builtin_amdgcn_mfma_f32_16x16x32_bf16(a1, bfr[j][1], o[j], 0, 0, 0);
      }
      int tl = (w * 2 + s) * 16 + qd * 4;
      float z0 = zs[tl], z1 = zs[tl + 1], z2 = zs[tl + 2], z3 = zs[tl + 3];
      size_t gb = (tok0 + ct * 128 + tl) * 512 + h64;
#pragma unroll
      for (int j = 0; j < 4; ++j) {
        int e = j * 16 + lr;
        Hb[gb + e] = f2b(o[j][0] * z0);
        Hb[gb + 512 + e] = f2b(o[j][1] * z1);
        Hb[gb + 1024 + e] = f2b(o[j][2] * z2);
        Hb[gb + 1536 + e] = f2b(o[j][3] * z3);
      }
    }
  }
}

// ---------------- K3: out = out_h @ Wo^T + bo (fp32 out) ----------------
__global__ void gemm_out(const u16* __restrict__ Hb, const u16* __restrict__ Wob,
                         const float* __restrict__ bo, float* __restrict__ out) {
  __shared__ u16 As[128 * 32];
  __shared__ u16 Bs[128 * 32];
  const int tid = threadIdx.x;
  const int blockM = blockIdx.y * 128;
  const int blockN = blockIdx.x * 128;
  const int lane = tid & 63;
  const int w = tid >> 6;
  const int wm = (w & 1) * 64;
  const int wn = (w >> 1) * 64;
  const int lr = lane & 15;
  const int qd = lane >> 4;

  f32x4 acc[4][4];
#pragma unroll
  for (int i = 0; i < 4; ++i)
#pragma unroll
    for (int j = 0; j < 4; ++j) acc[i][j] = {0.f, 0.f, 0.f, 0.f};

  for (int k0 = 0; k0 < 512; k0 += 32) {
    __syncthreads();
#pragma unroll
    for (int j = 0; j < 2; ++j) {
      int idx = j * 256 + tid;
      int row = idx >> 2, seg = idx & 3;
      ASYNC_LD16(Hb + (size_t)(blockM + row) * 512 + k0 + seg * 8, As + idx * 8);
      ASYNC_LD16(Wob + (size_t)(blockN + row) * 512 + k0 + seg * 8, Bs + idx * 8);
    }
    __syncthreads();
    short8 a[4], b[4];
#pragma unroll
    for (int i = 0; i < 4; ++i) a[i] = *(const short8*)&As[(wm + i * 16 + lr) * 32 + qd * 8];
#pragma unroll
    for (int j = 0; j < 4; ++j) b[j] = *(const short8*)&Bs[(wn + j * 16 + lr) * 32 + qd * 8];
#pragma unroll
    for (int i = 0; i < 4; ++i)
#pragma unroll
      for (int j = 0; j < 4; ++j)
        acc[i][j] = __builtin_amdgcn_mfma_f32_16x16x32_bf16(a[i], b[j], acc[i][j], 0, 0, 0);
  }

#pragma unroll
  for (int j = 0; j < 4; ++j) {
    int col = blockN + wn + j * 16 + lr;
    float bsv = bo[col];
#pragma unroll
    for (int i = 0; i < 4; ++i) {
#pragma unroll
      for (int r = 0; r < 4; ++r) {
        int row = blockM + wm + i * 16 + qd * 4 + r;
        out[(size_t)row * 512 + col] = acc[i][j][r] + bsv;
      }
    }
  }
}

// ---------------- launch ----------------
extern "C" void kernel_launch(void* const* d_in, const int* in_sizes, int n_in,
                              void* d_out, int out_size, void* d_ws, size_t ws_size,
                              hipStream_t stream) {
  const float* x  = (const float*)d_in[0];
  const float* Wq = (const float*)d_in[1];
  const float* bq = (const float*)d_in[2];
  const float* Wk = (const float*)d_in[3];
  const float* bk = (const float*)d_in[4];
  const float* Wv = (const float*)d_in[5];
  const float* bv = (const float*)d_in[6];
  const float* Wo = (const float*)d_in[7];
  const float* bo = (const float*)d_in[8];
  float* out = (float*)d_out;

  char* ws = (char*)d_ws;
  u16* xb   = (u16*)(ws);                 // 64 MB  (reused as Hb)
  u16* Wqkv = (u16*)(ws + 0x04000000ull); // 1.5 MB
  u16* Wob  = (u16*)(ws + 0x04200000ull); // 0.5 MB
  u16* Qb   = (u16*)(ws + 0x04400000ull); // 64 MB
  u16* Ktg  = (u16*)(ws + 0x08400000ull); // 64 MB [br][chan][tok]
  u16* Vtg  = (u16*)(ws + 0x0C400000ull); // 64 MB [br][chan][tok]
  u16* Hb   = xb;

  hipLaunchKernelGGL(convert_x, dim3(32768), dim3(256), 0, stream, x, xb);
  hipLaunchKernelGGL(convert_w, dim3(1024), dim3(256), 0, stream, Wq, Wk, Wv, Wo, Wqkv, Wob);
  hipLaunchKernelGGL(gemm_qkv, dim3(12, 512), dim3(256), 0, stream, xb, Wqkv, bq, bk, bv, Qb, Ktg, Vtg);
  hipLaunchKernelGGL(attn, dim3(1024), dim3(256), 0, stream, Qb, Ktg, Vtg, Hb);
  hipLaunchKernelGGL(gemm_out, dim3(4, 512), dim3(256), 0, stream, Hb, Wob, bo, out);
}